// Round 6
// baseline (56.429 us; speedup 1.0000x reference)
//
#include <hip/hip_runtime.h>
#include <math.h>

#define INV_TWO_PI_F 0.15915494309189535f

typedef float vfloat4 __attribute__((ext_vector_type(4)));  // valid for nontemporal builtin

// Hardware sin/cos take REVOLUTIONS: v_sin(r) = sin(2*pi*r). Reduce with fract.
__device__ __forceinline__ void sincos_rev(float rev, float* s, float* c) {
    float r = rev - floorf(rev);
    *s = __builtin_amdgcn_sinf(r);
    *c = __builtin_amdgcn_cosf(r);
}

// ---------------------------------------------------------------------------
// Single fused kernel (R4 structure: block owns ROWS *consecutive* rows).
// Threads 0..ROWS*4-1 build per-(row,period) coefficients into LDS:
//   P = s_amp*mr/|m| (sin coeff), Q = s_amp*mi/|m| (cos coeff)
// Every thread builds its own sin/cos table slice for its 4 consecutive t
// (hardware v_sin/v_cos, revolutions domain). Then the sweep:
//   out[n*T+t] = c0 + b*tv[t] + sum_i (P_i*sin(2pi f_i tv[t]) + Q_i*cos(...))
// R6 delta vs R4: output stores are NON-TEMPORAL (streaming, no L2 allocate).
// ---------------------------------------------------------------------------
template <int ROWS, int KT>
__global__ __launch_bounds__(256, 4) void k_all(
        const float* __restrict__ tv,   const float* __restrict__ co,
        const float* __restrict__ lt,   const float* __restrict__ amp,
        const float* __restrict__ ph,   const float* __restrict__ w,
        const float* __restrict__ bmin, const float* __restrict__ bmax,
        const int* __restrict__ nbr,
        float* __restrict__ out, int N, int T, int Krt) {
    const int tid   = threadIdx.x;
    const int nq    = (T + 3) >> 2;              // number of t-quads
    const int qi    = blockIdx.y * 256 + tid;    // this thread's quad
    const int t0    = qi * 4;
    const bool act  = (qi < nq);
    const int nbase = blockIdx.x * ROWS;
    const int K     = KT ? KT : Krt;

    // Per-row: P0 Q0 P1 Q1 | P2 Q2 P3 Q3 | c0 b pad pad  (3 x float4)
    __shared__ float cf[ROWS][12];

    // ---- Phase B: coefficients for this block's rows -> LDS ----
    if (tid < ROWS * 4) {
        const int r = tid >> 2, i = tid & 3;
        const int n = nbase + r;
        if (n < N) {
            float na = 0.f, ar = 0.f, ai = 0.f;
#pragma unroll
            for (int k = 0; k < K; ++k) {
                const float wk = w[(size_t)n * K + k];
                const int   m  = nbr[(size_t)n * K + k];
                const float am = amp[(size_t)m * 4 + i];
                const float pm = ph[(size_t)m * 4 + i];
                float s, c;
                sincos_rev(pm * INV_TWO_PI_F, &s, &c);
                na = fmaf(am, wk, na);
                ar = fmaf(c, wk, ar);
                ai = fmaf(s, wk, ai);
            }
            const float a0 = amp[(size_t)n * 4 + i];
            const float p0 = ph[(size_t)n * 4 + i];
            float s_amp = fmaf(0.15f, na, 0.85f * a0);
            s_amp = fminf(fmaxf(s_amp, bmin[(size_t)i * N + n]),
                          bmax[(size_t)i * N + n]);
            float ci, cr;
            sincos_rev(p0 * INV_TWO_PI_F, &ci, &cr);
            const float mr  = fmaf(0.1f, ar, 0.9f * cr);
            const float mi  = fmaf(0.1f, ai, 0.9f * ci);
            const float inv = rsqrtf(fmaf(mr, mr, mi * mi));  // |m| >= 0.8
            cf[r][2 * i]     = s_amp * mr * inv;
            cf[r][2 * i + 1] = s_amp * mi * inv;
            if (i == 0) {
                cf[r][8]  = co[n];
                cf[r][9]  = lt[n];
                cf[r][10] = 0.f;
                cf[r][11] = 0.f;
            }
        }
    }

    // ---- Phase A: per-thread sin/cos table (overlaps Phase B's gathers) ----
    const float freqs[4] = {4.0f, 2.0f, 1.0f, 0.5f};
    float tvq[4], sn[4][4], cs[4][4];
    if (act) {
#pragma unroll
        for (int q = 0; q < 4; ++q) {
            int t = t0 + q; if (t > T - 1) t = T - 1;
            tvq[q] = tv[t];
#pragma unroll
            for (int i = 0; i < 4; ++i)
                sincos_rev(freqs[i] * tvq[q], &sn[q][i], &cs[q][i]);
        }
    }
    __syncthreads();

    // ---- Phase C: sweep (zero global reads; LDS broadcast reads only) ----
    float* dst = out + (size_t)nbase * T + t0;
#pragma unroll 2
    for (int r = 0; r < ROWS; ++r, dst += T) {
        const int n = nbase + r;
        if (n >= N) break;
        const float4 PQ0 = *(const float4*)&cf[r][0];
        const float4 PQ1 = *(const float4*)&cf[r][4];
        const float4 CB  = *(const float4*)&cf[r][8];
        if (!act) continue;
        float v[4];
#pragma unroll
        for (int q = 0; q < 4; ++q) {
            float x = fmaf(CB.y, tvq[q], CB.x);
            x = fmaf(PQ0.x, sn[q][0], x);
            x = fmaf(PQ0.y, cs[q][0], x);
            x = fmaf(PQ0.z, sn[q][1], x);
            x = fmaf(PQ0.w, cs[q][1], x);
            x = fmaf(PQ1.x, sn[q][2], x);
            x = fmaf(PQ1.y, cs[q][2], x);
            x = fmaf(PQ1.z, sn[q][3], x);
            x = fmaf(PQ1.w, cs[q][3], x);
            v[q] = x;
        }
        if (t0 + 3 < T) {
            vfloat4 o; o.x = v[0]; o.y = v[1]; o.z = v[2]; o.w = v[3];
            __builtin_nontemporal_store(o, (vfloat4*)dst);
        } else {
#pragma unroll
            for (int q = 0; q < 4; ++q)
                if (t0 + q < T) __builtin_nontemporal_store(v[q], dst + q);
        }
    }
}

extern "C" void kernel_launch(void* const* d_in, const int* in_sizes, int n_in,
                              void* d_out, int out_size, void* d_ws, size_t ws_size,
                              hipStream_t stream) {
    const float* tv   = (const float*)d_in[0];
    const float* co   = (const float*)d_in[1];
    const float* lt   = (const float*)d_in[2];
    const float* amp  = (const float*)d_in[3];
    const float* ph   = (const float*)d_in[4];
    const float* w    = (const float*)d_in[5];
    const float* bmin = (const float*)d_in[6];
    const float* bmax = (const float*)d_in[7];
    const int*   nbr  = (const int*)d_in[8];

    const int T = in_sizes[0];
    const int N = in_sizes[1];
    const int K = in_sizes[5] / N;

    float* out = (float*)d_out;

    constexpr int ROWS = 25;
    const int nq = (T + 3) / 4;
    dim3 grid((N + ROWS - 1) / ROWS, (nq + 255) / 256);
    if (K == 8) {
        k_all<ROWS, 8><<<grid, 256, 0, stream>>>(tv, co, lt, amp, ph, w, bmin,
                                                 bmax, nbr, out, N, T, K);
    } else {
        k_all<ROWS, 0><<<grid, 256, 0, stream>>>(tv, co, lt, amp, ph, w, bmin,
                                                 bmax, nbr, out, N, T, K);
    }
}

// Round 7
// 45.724 us; speedup vs baseline: 1.2341x; 1.2341x over previous
//
#include <hip/hip_runtime.h>
#include <math.h>

#define INV_TWO_PI_F 0.15915494309189535f

// Hardware sin/cos take REVOLUTIONS: v_sin(r) = sin(2*pi*r). Reduce with fract.
__device__ __forceinline__ void sincos_rev(float rev, float* s, float* c) {
    float r = rev - floorf(rev);
    *s = __builtin_amdgcn_sinf(r);
    *c = __builtin_amdgcn_cosf(r);
}

// ---------------------------------------------------------------------------
// Single fused kernel (R4 structure: block owns ROWS consecutive rows).
// R7 delta vs R4: ROWS 25 -> 50, so grid = 1000 blocks <= 1024 resident slots
// (launch_bounds 256,4): one co-resident cohort, all phase-B gather ramps
// overlap at kernel start, then a single uninterrupted store stream.
//
// Threads 0..ROWS*4-1 build per-(row,period) coefficients into LDS:
//   P = s_amp*mr/|m| (sin coeff), Q = s_amp*mi/|m| (cos coeff)
// Every thread builds its own sin/cos table slice for its 4 consecutive t
// (hardware v_sin/v_cos, revolutions domain). Then the sweep:
//   out[n*T+t] = c0 + b*tv[t] + sum_i (P_i*sin(2pi f_i tv[t]) + Q_i*cos(...))
// ---------------------------------------------------------------------------
template <int ROWS, int KT>
__global__ __launch_bounds__(256, 4) void k_all(
        const float* __restrict__ tv,   const float* __restrict__ co,
        const float* __restrict__ lt,   const float* __restrict__ amp,
        const float* __restrict__ ph,   const float* __restrict__ w,
        const float* __restrict__ bmin, const float* __restrict__ bmax,
        const int* __restrict__ nbr,
        float* __restrict__ out, int N, int T, int Krt) {
    const int tid   = threadIdx.x;
    const int nq    = (T + 3) >> 2;              // number of t-quads
    const int qi    = blockIdx.y * 256 + tid;    // this thread's quad
    const int t0    = qi * 4;
    const bool act  = (qi < nq);
    const int nbase = blockIdx.x * ROWS;
    const int K     = KT ? KT : Krt;

    // Per-row: P0 Q0 P1 Q1 | P2 Q2 P3 Q3 | c0 b pad pad  (3 x float4)
    __shared__ float cf[ROWS][12];

    // ---- Phase B: coefficients for this block's rows -> LDS ----
    if (tid < ROWS * 4) {
        const int r = tid >> 2, i = tid & 3;
        const int n = nbase + r;
        if (n < N) {
            float na = 0.f, ar = 0.f, ai = 0.f;
#pragma unroll
            for (int k = 0; k < K; ++k) {
                const float wk = w[(size_t)n * K + k];
                const int   m  = nbr[(size_t)n * K + k];
                const float am = amp[(size_t)m * 4 + i];
                const float pm = ph[(size_t)m * 4 + i];
                float s, c;
                sincos_rev(pm * INV_TWO_PI_F, &s, &c);
                na = fmaf(am, wk, na);
                ar = fmaf(c, wk, ar);
                ai = fmaf(s, wk, ai);
            }
            const float a0 = amp[(size_t)n * 4 + i];
            const float p0 = ph[(size_t)n * 4 + i];
            float s_amp = fmaf(0.15f, na, 0.85f * a0);
            s_amp = fminf(fmaxf(s_amp, bmin[(size_t)i * N + n]),
                          bmax[(size_t)i * N + n]);
            float ci, cr;
            sincos_rev(p0 * INV_TWO_PI_F, &ci, &cr);
            const float mr  = fmaf(0.1f, ar, 0.9f * cr);
            const float mi  = fmaf(0.1f, ai, 0.9f * ci);
            const float inv = rsqrtf(fmaf(mr, mr, mi * mi));  // |m| >= 0.8
            cf[r][2 * i]     = s_amp * mr * inv;
            cf[r][2 * i + 1] = s_amp * mi * inv;
            if (i == 0) {
                cf[r][8]  = co[n];
                cf[r][9]  = lt[n];
                cf[r][10] = 0.f;
                cf[r][11] = 0.f;
            }
        }
    }

    // ---- Phase A: per-thread sin/cos table (overlaps Phase B's gathers) ----
    const float freqs[4] = {4.0f, 2.0f, 1.0f, 0.5f};
    float tvq[4], sn[4][4], cs[4][4];
    if (act) {
#pragma unroll
        for (int q = 0; q < 4; ++q) {
            int t = t0 + q; if (t > T - 1) t = T - 1;
            tvq[q] = tv[t];
#pragma unroll
            for (int i = 0; i < 4; ++i)
                sincos_rev(freqs[i] * tvq[q], &sn[q][i], &cs[q][i]);
        }
    }
    __syncthreads();

    // ---- Phase C: sweep (zero global reads; LDS broadcast reads only) ----
    float* dst = out + (size_t)nbase * T + t0;
#pragma unroll 2
    for (int r = 0; r < ROWS; ++r, dst += T) {
        const int n = nbase + r;
        if (n >= N) break;
        const float4 PQ0 = *(const float4*)&cf[r][0];
        const float4 PQ1 = *(const float4*)&cf[r][4];
        const float4 CB  = *(const float4*)&cf[r][8];
        if (!act) continue;
        float v[4];
#pragma unroll
        for (int q = 0; q < 4; ++q) {
            float x = fmaf(CB.y, tvq[q], CB.x);
            x = fmaf(PQ0.x, sn[q][0], x);
            x = fmaf(PQ0.y, cs[q][0], x);
            x = fmaf(PQ0.z, sn[q][1], x);
            x = fmaf(PQ0.w, cs[q][1], x);
            x = fmaf(PQ1.x, sn[q][2], x);
            x = fmaf(PQ1.y, cs[q][2], x);
            x = fmaf(PQ1.z, sn[q][3], x);
            x = fmaf(PQ1.w, cs[q][3], x);
            v[q] = x;
        }
        if (t0 + 3 < T) {
            float4 o; o.x = v[0]; o.y = v[1]; o.z = v[2]; o.w = v[3];
            *(float4*)dst = o;
        } else {
#pragma unroll
            for (int q = 0; q < 4; ++q)
                if (t0 + q < T) dst[q] = v[q];
        }
    }
}

extern "C" void kernel_launch(void* const* d_in, const int* in_sizes, int n_in,
                              void* d_out, int out_size, void* d_ws, size_t ws_size,
                              hipStream_t stream) {
    const float* tv   = (const float*)d_in[0];
    const float* co   = (const float*)d_in[1];
    const float* lt   = (const float*)d_in[2];
    const float* amp  = (const float*)d_in[3];
    const float* ph   = (const float*)d_in[4];
    const float* w    = (const float*)d_in[5];
    const float* bmin = (const float*)d_in[6];
    const float* bmax = (const float*)d_in[7];
    const int*   nbr  = (const int*)d_in[8];

    const int T = in_sizes[0];
    const int N = in_sizes[1];
    const int K = in_sizes[5] / N;

    float* out = (float*)d_out;

    constexpr int ROWS = 50;   // 1000 blocks -> single co-resident cohort
    const int nq = (T + 3) / 4;
    dim3 grid((N + ROWS - 1) / ROWS, (nq + 255) / 256);
    if (K == 8) {
        k_all<ROWS, 8><<<grid, 256, 0, stream>>>(tv, co, lt, amp, ph, w, bmin,
                                                 bmax, nbr, out, N, T, K);
    } else {
        k_all<ROWS, 0><<<grid, 256, 0, stream>>>(tv, co, lt, amp, ph, w, bmin,
                                                 bmax, nbr, out, N, T, K);
    }
}

// Round 8
// 40.465 us; speedup vs baseline: 1.3945x; 1.1300x over previous
//
#include <hip/hip_runtime.h>
#include <math.h>

#define INV_TWO_PI_F 0.15915494309189535f

// Hardware sin/cos take REVOLUTIONS: v_sin(r) = sin(2*pi*r). Reduce with fract.
__device__ __forceinline__ void sincos_rev(float rev, float* s, float* c) {
    float r = rev - floorf(rev);
    *s = __builtin_amdgcn_sinf(r);
    *c = __builtin_amdgcn_cosf(r);
}

// ---------------------------------------------------------------------------
// Single fused kernel. Block owns ROWS consecutive rows.
// R8 delta vs R7: the sweep is split into bursts of U rows — compute U rows
// into registers (LDS cf reads + FMAs), THEN issue U back-to-back dwordx4
// stores. Same bytes/addresses/FMAs; only per-wave store clustering changes
// (per-wave store MLP 1-2 -> ~U, mimicking the 7 TB/s fill's back-to-back
// store issue).
//
// Threads 0..ROWS*4-1 build per-(row,period) coefficients into LDS:
//   P = s_amp*mr/|m| (sin coeff), Q = s_amp*mi/|m| (cos coeff)
// Every thread builds its own sin/cos table slice for its 4 consecutive t
// (hardware v_sin/v_cos, revolutions domain). Then the sweep:
//   out[n*T+t] = c0 + b*tv[t] + sum_i (P_i*sin(2pi f_i tv[t]) + Q_i*cos(...))
// ---------------------------------------------------------------------------
template <int ROWS, int U, int KT>
__global__ __launch_bounds__(256, 4) void k_all(
        const float* __restrict__ tv,   const float* __restrict__ co,
        const float* __restrict__ lt,   const float* __restrict__ amp,
        const float* __restrict__ ph,   const float* __restrict__ w,
        const float* __restrict__ bmin, const float* __restrict__ bmax,
        const int* __restrict__ nbr,
        float* __restrict__ out, int N, int T, int Krt) {
    const int tid   = threadIdx.x;
    const int nq    = (T + 3) >> 2;              // number of t-quads
    const int qi    = blockIdx.y * 256 + tid;    // this thread's quad
    const int t0    = qi * 4;
    const bool act  = (qi < nq);
    const int nbase = blockIdx.x * ROWS;
    const int K     = KT ? KT : Krt;

    // Per-row: P0 Q0 P1 Q1 | P2 Q2 P3 Q3 | c0 b pad pad  (3 x float4)
    __shared__ float cf[ROWS][12];

    // ---- Phase B: coefficients for this block's rows -> LDS ----
    if (tid < ROWS * 4) {
        const int r = tid >> 2, i = tid & 3;
        const int n = nbase + r;
        if (n < N) {
            float na = 0.f, ar = 0.f, ai = 0.f;
#pragma unroll
            for (int k = 0; k < K; ++k) {
                const float wk = w[(size_t)n * K + k];
                const int   m  = nbr[(size_t)n * K + k];
                const float am = amp[(size_t)m * 4 + i];
                const float pm = ph[(size_t)m * 4 + i];
                float s, c;
                sincos_rev(pm * INV_TWO_PI_F, &s, &c);
                na = fmaf(am, wk, na);
                ar = fmaf(c, wk, ar);
                ai = fmaf(s, wk, ai);
            }
            const float a0 = amp[(size_t)n * 4 + i];
            const float p0 = ph[(size_t)n * 4 + i];
            float s_amp = fmaf(0.15f, na, 0.85f * a0);
            s_amp = fminf(fmaxf(s_amp, bmin[(size_t)i * N + n]),
                          bmax[(size_t)i * N + n]);
            float ci, cr;
            sincos_rev(p0 * INV_TWO_PI_F, &ci, &cr);
            const float mr  = fmaf(0.1f, ar, 0.9f * cr);
            const float mi  = fmaf(0.1f, ai, 0.9f * ci);
            const float inv = rsqrtf(fmaf(mr, mr, mi * mi));  // |m| >= 0.8
            cf[r][2 * i]     = s_amp * mr * inv;
            cf[r][2 * i + 1] = s_amp * mi * inv;
            if (i == 0) {
                cf[r][8]  = co[n];
                cf[r][9]  = lt[n];
                cf[r][10] = 0.f;
                cf[r][11] = 0.f;
            }
        }
    }

    // ---- Phase A: per-thread sin/cos table (overlaps Phase B's gathers) ----
    const float freqs[4] = {4.0f, 2.0f, 1.0f, 0.5f};
    float tvq[4], sn[4][4], cs[4][4];
    if (act) {
#pragma unroll
        for (int q = 0; q < 4; ++q) {
            int t = t0 + q; if (t > T - 1) t = T - 1;
            tvq[q] = tv[t];
#pragma unroll
            for (int i = 0; i < 4; ++i)
                sincos_rev(freqs[i] * tvq[q], &sn[q][i], &cs[q][i]);
        }
    }
    __syncthreads();

    // ---- Phase C: sweep in bursts of U rows ----
    if (act) {
        float* dst = out + (size_t)nbase * T + t0;
#pragma unroll 1
        for (int rb = 0; rb < ROWS; rb += U) {
            float v[U][4];
            // compute U rows into registers
#pragma unroll
            for (int u = 0; u < U; ++u) {
                const int r = rb + u;
                const float4 PQ0 = *(const float4*)&cf[r][0];
                const float4 PQ1 = *(const float4*)&cf[r][4];
                const float4 CB  = *(const float4*)&cf[r][8];
#pragma unroll
                for (int q = 0; q < 4; ++q) {
                    float x = fmaf(CB.y, tvq[q], CB.x);
                    x = fmaf(PQ0.x, sn[q][0], x);
                    x = fmaf(PQ0.y, cs[q][0], x);
                    x = fmaf(PQ0.z, sn[q][1], x);
                    x = fmaf(PQ0.w, cs[q][1], x);
                    x = fmaf(PQ1.x, sn[q][2], x);
                    x = fmaf(PQ1.y, cs[q][2], x);
                    x = fmaf(PQ1.z, sn[q][3], x);
                    x = fmaf(PQ1.w, cs[q][3], x);
                    v[u][q] = x;
                }
            }
            // burst-store U rows back-to-back
            if (t0 + 3 < T) {
#pragma unroll
                for (int u = 0; u < U; ++u) {
                    const int n = nbase + rb + u;
                    if (n >= N) break;
                    float4 o; o.x = v[u][0]; o.y = v[u][1]; o.z = v[u][2]; o.w = v[u][3];
                    *(float4*)(dst + (size_t)(rb + u) * T) = o;
                }
            } else {
#pragma unroll
                for (int u = 0; u < U; ++u) {
                    const int n = nbase + rb + u;
                    if (n >= N) break;
#pragma unroll
                    for (int q = 0; q < 4; ++q)
                        if (t0 + q < T) *(dst + (size_t)(rb + u) * T + q) = v[u][q];
                }
            }
        }
    }
}

extern "C" void kernel_launch(void* const* d_in, const int* in_sizes, int n_in,
                              void* d_out, int out_size, void* d_ws, size_t ws_size,
                              hipStream_t stream) {
    const float* tv   = (const float*)d_in[0];
    const float* co   = (const float*)d_in[1];
    const float* lt   = (const float*)d_in[2];
    const float* amp  = (const float*)d_in[3];
    const float* ph   = (const float*)d_in[4];
    const float* w    = (const float*)d_in[5];
    const float* bmin = (const float*)d_in[6];
    const float* bmax = (const float*)d_in[7];
    const int*   nbr  = (const int*)d_in[8];

    const int T = in_sizes[0];
    const int N = in_sizes[1];
    const int K = in_sizes[5] / N;

    float* out = (float*)d_out;

    constexpr int ROWS = 50;   // 1000 blocks, single co-resident cohort
    constexpr int U    = 10;   // store burst depth (40 VGPRs of staging)
    const int nq = (T + 3) / 4;
    dim3 grid((N + ROWS - 1) / ROWS, (nq + 255) / 256);
    if (K == 8) {
        k_all<ROWS, U, 8><<<grid, 256, 0, stream>>>(tv, co, lt, amp, ph, w, bmin,
                                                    bmax, nbr, out, N, T, K);
    } else {
        k_all<ROWS, U, 0><<<grid, 256, 0, stream>>>(tv, co, lt, amp, ph, w, bmin,
                                                    bmax, nbr, out, N, T, K);
    }
}